// Round 7
// baseline (709.082 us; speedup 1.0000x reference)
//
#include <hip/hip_runtime.h>
#include <stdint.h>

#define NN 100000     // N_SRC == N_TGT
#define NE 1600000
#define DD 128
#define HB 1024       // hist/scatter1 grid (logical)
#define G8 12544      // nodes per top bucket = 128 * 98
#define SUBN 98       // nodes per sub-bucket
#define NSUB 128      // sub-buckets per top bucket
#define NND 100352    // padded node count = 8 * G8
#define K2 16         // chunks per top bucket (hist2/scatter2)
#define RCAP 2304     // record cap per sub-bucket (mean 1568, sd ~40)

typedef unsigned short u16;
typedef unsigned long long u64;
typedef short short8 __attribute__((ext_vector_type(8)));
typedef float floatx4 __attribute__((ext_vector_type(4)));
typedef float floatx2 __attribute__((ext_vector_type(2)));
typedef int intx4 __attribute__((ext_vector_type(4)));

// ===================== helpers =====================
__device__ static inline u16 f2bf(float f){
  unsigned u = __float_as_uint(f);
  unsigned r = u + 0x7FFFu + ((u >> 16) & 1u);   // RNE
  return (u16)(r >> 16);
}

// ===================== threefry2x32 (JAX-compatible) =====================
__host__ __device__ static inline unsigned rotl32(unsigned x, int r){
  return (x << r) | (x >> (32 - r));
}

__host__ __device__ static inline void tf2x32(unsigned k0, unsigned k1,
                                              unsigned c0, unsigned c1,
                                              unsigned &o0, unsigned &o1)
{
  const unsigned ks2 = k0 ^ k1 ^ 0x1BD11BDAu;
  unsigned x0 = c0 + k0, x1 = c1 + k1;
#define TFR(r) { x0 += x1; x1 = rotl32(x1, (r)); x1 ^= x0; }
  TFR(13) TFR(15) TFR(26) TFR(6)   x0 += k1;  x1 += ks2 + 1u;
  TFR(17) TFR(29) TFR(16) TFR(24)  x0 += ks2; x1 += k0 + 2u;
  TFR(13) TFR(15) TFR(26) TFR(6)   x0 += k0;  x1 += k1 + 3u;
  TFR(17) TFR(29) TFR(16) TFR(24)  x0 += k1;  x1 += ks2 + 4u;
  TFR(13) TFR(15) TFR(26) TFR(6)   x0 += ks2; x1 += k0 + 5u;
#undef TFR
  o0 = x0; o1 = x1;
}

// keep-decision for one element (bit-identical to harness-verified drop_scale)
__device__ static inline int drop_keep(unsigned k0, unsigned k1, unsigned j)
{
  unsigned o0, o1;
  tf2x32(k0, k1, 0u, j, o0, o1);
  const unsigned bits = o0 ^ o1;
  const float u = __uint_as_float((bits >> 9) | 0x3F800000u) - 1.0f;
  return u < 0.9f;
}

// bf16x8 (as uint4) unpack-accumulate into packed f32x2 accumulators
__device__ static inline void acc4(floatx2 &p0, floatx2 &p1, floatx2 &p2,
                                   floatx2 &p3, uint4 v){
  floatx2 t0, t1, t2, t3;
  t0[0] = __uint_as_float(v.x << 16); t0[1] = __uint_as_float(v.x & 0xFFFF0000u);
  t1[0] = __uint_as_float(v.y << 16); t1[1] = __uint_as_float(v.y & 0xFFFF0000u);
  t2[0] = __uint_as_float(v.z << 16); t2[1] = __uint_as_float(v.z & 0xFFFF0000u);
  t3[0] = __uint_as_float(v.w << 16); t3[1] = __uint_as_float(v.w & 0xFFFF0000u);
  p0 += t0; p1 += t1; p2 += t2; p3 += t3;
}

// ========== fused prep: cvt (12500) + hist (1024) + weight prep (52) =========
#define CVB 12500
__global__ __launch_bounds__(256) void k_pre(
    const float* __restrict__ ina, const float* __restrict__ inb,
    u16* __restrict__ oa, u16* __restrict__ ob, int n8,
    const int* __restrict__ e_dst, const int* __restrict__ r_dst,
    int* __restrict__ hist,
    const float* __restrict__ Wl_tgt, const float* __restrict__ Wr_tgt,
    const float* __restrict__ Wl_src, const float* __restrict__ Wr_src,
    const float* __restrict__ Wo,
    u16* __restrict__ Wsw0, u16* __restrict__ Wsw1, u16* __restrict__ Wsw2,
    u16* __restrict__ Wswo)
{
  const int blk = blockIdx.x;
  const int t = threadIdx.x;
  if (blk < CVB){
    // -------- fp32 -> bf16 convert --------
    int i = blk * 256 + t;
    const float* in = ina; u16* out = oa;
    if (i >= n8){ i -= n8; in = inb; out = ob; }
    floatx4 a = __builtin_nontemporal_load((const floatx4*)in + (size_t)i * 2);
    floatx4 c = __builtin_nontemporal_load((const floatx4*)in + (size_t)i * 2 + 1);
    u16 v[8] = { f2bf(a[0]), f2bf(a[1]), f2bf(a[2]), f2bf(a[3]),
                 f2bf(c[0]), f2bf(c[1]), f2bf(c[2]), f2bf(c[3]) };
    *(uint4*)(out + (size_t)i * 8) = *(const uint4*)v;
  } else if (blk < CVB + HB){
    // -------- level-1 histogram --------
    const int hb = blk - CVB;
    __shared__ int h[16];
    if (t < 16) h[t] = 0;
    __syncthreads();
    const int QT = 2 * (NE / 4);
    for (int i = hb * 256 + t; i < QT; i += HB * 256){
      int dir = (i >= NE / 4);
      int qi = dir ? i - NE / 4 : i;
      const int* dp = dir ? r_dst : e_dst;
      intx4 d = __builtin_nontemporal_load((const intx4*)dp + qi);
      int bb = dir << 3;
      atomicAdd(&h[bb + d.x / G8], 1);
      atomicAdd(&h[bb + d.y / G8], 1);
      atomicAdd(&h[bb + d.z / G8], 1);
      atomicAdd(&h[bb + d.w / G8], 1);
    }
    __syncthreads();
    if (t < 16) hist[t * HB + hb] = h[t];
  } else {
    // -------- weight pre-swizzle --------
    int b = blk - CVB - HB;
    if (b < 48){
      const float *Wl, *Wr; u16* dst;
      if (b < 16){ Wl = Wl_tgt; Wr = Wr_tgt; dst = Wsw0; }
      else if (b < 32){ Wl = Wl_src; Wr = Wr_src; dst = Wsw1; b -= 16; }
      else { Wl = Wl_src + 16384; Wr = Wr_src + 16384; dst = Wsw2; b -= 32; }
      int idx = b * 256 + t;
      int lane = idx & 63, tile = idx >> 6;
      int kt = tile >> 3, nt = tile & 7;
      int n = nt * 16 + (lane & 15);
      int kb = kt * 32 + (lane >> 4) * 8;
      u16 v[8];
      #pragma unroll
      for (int j = 0; j < 8; ++j){
        int k = kb + j;
        float w = (k < 128) ? Wl[(size_t)k * 128 + n] : Wr[(size_t)(k - 128) * 128 + n];
        v[j] = f2bf(w);
      }
      *(uint4*)(dst + (size_t)idx * 8) = *(const uint4*)v;
    } else {
      int idx = (b - 48) * 256 + t;
      int lane = idx & 63, tile = idx >> 6;
      int kt = tile >> 2, nt = tile & 3;
      int n = nt * 16 + (lane & 15);
      int kb = kt * 32 + (lane >> 4) * 8;
      u16 v[8];
      #pragma unroll
      for (int j = 0; j < 8; ++j)
        v[j] = f2bf(Wo[(size_t)(kb + j) * 64 + n]);
      *(uint4*)(Wswo + (size_t)idx * 8) = *(const uint4*)v;
    }
  }
}

// Exclusive scan over hist[16*HB] (bucket-major); hist[16*HB] = total.
__global__ __launch_bounds__(256) void k_scanA(int* __restrict__ hist){
  __shared__ int sh[16 * HB];
  __shared__ int tot[256];
  const int t = threadIdx.x;
  const int N = 16 * HB;
  for (int k = t; k < N; k += 256) sh[k] = hist[k];
  __syncthreads();
  int s = 0;
  #pragma unroll 4
  for (int k = 0; k < 64; ++k)
    s += sh[(t >> 4) * HB + (t & 15) + (k << 4)];
  tot[t] = s;
  __syncthreads();
  int v = s;
  for (int off = 1; off < 256; off <<= 1){
    int u = (t >= off) ? tot[t - off] : 0;
    __syncthreads();
    tot[t] += u;
    __syncthreads();
  }
  int run = tot[t] - v;
  for (int k = 0; k < 64; ++k){
    int idx = (t >> 4) * HB + (t & 15) + (k << 4);
    int xv = sh[idx];
    sh[idx] = run;
    run += xv;
  }
  __syncthreads();
  for (int k = t; k < N; k += 256) hist[k] = sh[k];
  if (t == 255) hist[N] = tot[255];   // grand total = 2*NE
}

// Scatter into 16 bucket-contiguous regions. Record = (node_local<<17)|src.
__global__ __launch_bounds__(256) void k_scatter1(const int* __restrict__ e_src,
                                                  const int* __restrict__ e_dst,
                                                  const int* __restrict__ r_src,
                                                  const int* __restrict__ r_dst,
                                                  const int* __restrict__ base,
                                                  unsigned* __restrict__ stage){
  __shared__ int cur[16];
  const int t = threadIdx.x;
  if (t < 16) cur[t] = base[t * HB + blockIdx.x];
  __syncthreads();
  const int QT = 2 * (NE / 4);
  for (int i = blockIdx.x * 256 + t; i < QT; i += HB * 256){
    int dir = (i >= NE / 4);
    int qi = dir ? i - NE / 4 : i;
    const int* dp = dir ? r_dst : e_dst;
    const int* sp = dir ? r_src : e_src;
    intx4 d = __builtin_nontemporal_load((const intx4*)dp + qi);
    intx4 sv = __builtin_nontemporal_load((const intx4*)sp + qi);
    int bb = dir << 3;
    int g, p;
    g = d.x / G8; p = atomicAdd(&cur[bb + g], 1);
    stage[p] = (unsigned)sv.x | ((unsigned)(d.x - g * G8) << 17);
    g = d.y / G8; p = atomicAdd(&cur[bb + g], 1);
    stage[p] = (unsigned)sv.y | ((unsigned)(d.y - g * G8) << 17);
    g = d.z / G8; p = atomicAdd(&cur[bb + g], 1);
    stage[p] = (unsigned)sv.z | ((unsigned)(d.z - g * G8) << 17);
    g = d.w / G8; p = atomicAdd(&cur[bb + g], 1);
    stage[p] = (unsigned)sv.w | ((unsigned)(d.w - g * G8) << 17);
  }
}

// ===================== level-2 partition: 128 sub-buckets per bucket =========
__global__ __launch_bounds__(256) void k_hist2(const unsigned* __restrict__ stage,
                                               const int* __restrict__ base,
                                               int* __restrict__ hist2){
  __shared__ int h2[NSUB];
  const int b16 = blockIdx.x / K2, k = blockIdx.x % K2;
  const int t = threadIdx.x;
  if (t < NSUB) h2[t] = 0;
  __syncthreads();
  const int beg = base[b16 * HB];
  const int end = base[(b16 + 1) * HB];
  for (int i = beg + k * 256 + t; i < end; i += K2 * 256){
    unsigned p = stage[i];
    atomicAdd(&h2[(int)(p >> 17) / SUBN], 1);
  }
  __syncthreads();
  if (t < NSUB) hist2[(b16 * NSUB + t) * K2 + k] = h2[t];
}

// Ordered exclusive scan over hist2[32768] (one block).
__global__ __launch_bounds__(256) void k_scanB(int* __restrict__ hist2){
  __shared__ int sh[16 * NSUB * K2];   // 128 KB
  __shared__ int tot[256];
  const int t = threadIdx.x;
  const int N = 16 * NSUB * K2;
  for (int k = t; k < N; k += 256) sh[k] = hist2[k];
  __syncthreads();
  int s = 0;
  for (int j = 0; j < 128; ++j) s += sh[t * 128 + j];
  tot[t] = s;
  __syncthreads();
  int v = s;
  for (int off = 1; off < 256; off <<= 1){
    int u = (t >= off) ? tot[t - off] : 0;
    __syncthreads();
    tot[t] += u;
    __syncthreads();
  }
  int run = tot[t] - v;
  for (int j = 0; j < 128; ++j){
    int xv = sh[t * 128 + j];
    sh[t * 128 + j] = run;
    run += xv;
  }
  __syncthreads();
  for (int k = t; k < N; k += 256) hist2[k] = sh[k];
}

// Scatter bucket -> sub-bucket-contiguous stage2.
__global__ __launch_bounds__(256) void k_scatter2(const unsigned* __restrict__ stage,
                                                  const int* __restrict__ base,
                                                  const int* __restrict__ h2s,
                                                  unsigned* __restrict__ stage2){
  __shared__ int cur[NSUB];
  const int b16 = blockIdx.x / K2, k = blockIdx.x % K2;
  const int t = threadIdx.x;
  if (t < NSUB) cur[t] = h2s[(b16 * NSUB + t) * K2 + k];
  __syncthreads();
  const int beg = base[b16 * HB];
  const int end = base[(b16 + 1) * HB];
  for (int i = beg + k * 256 + t; i < end; i += K2 * 256){
    unsigned p = stage[i];
    int pos = atomicAdd(&cur[(int)(p >> 17) / SUBN], 1);
    stage2[pos] = p;
  }
}

// ===================== LDS counting-sort -> COMPACT csr + ptr ===============
// (reverted to node-key version: src-sweep sub-key was falsified in R6)
__global__ __launch_bounds__(256) void k_fill4(const unsigned* __restrict__ stage2,
                                               const int* __restrict__ h2s,
                                               int* __restrict__ ptr,
                                               int* __restrict__ csr){
  __shared__ unsigned rec[RCAP];
  __shared__ unsigned srt[RCAP];
  __shared__ int ldeg[SUBN], lptr[SUBN], lcur[SUBN];
  const int sb = blockIdx.x;              // 0..2047
  const int b16 = sb >> 7, sub = sb & 127;
  const int dir = b16 >> 3, g = b16 & 7;
  const int t = threadIdx.x;
  const int beg = h2s[sb * K2];
  const int end = (sb == 2047) ? 2 * NE : h2s[(sb + 1) * K2];
  int n = end - beg;
  if (n > RCAP) n = RCAP;
  for (int i = t; i < n; i += 256) rec[i] = stage2[beg + i];
  if (t < SUBN) ldeg[t] = 0;
  __syncthreads();
  const int nl0 = sub * SUBN;
  for (int i = t; i < n; i += 256)
    atomicAdd(&ldeg[(int)(rec[i] >> 17) - nl0], 1);
  __syncthreads();
  if (t == 0){
    int run = 0;
    for (int s = 0; s < SUBN; ++s){ lptr[s] = run; lcur[s] = run; run += ldeg[s]; }
  }
  __syncthreads();
  for (int i = t; i < n; i += 256){
    int rl = (int)(rec[i] >> 17) - nl0;
    int pos = atomicAdd(&lcur[rl], 1);
    srt[pos] = rec[i] & 0x1FFFFu;
  }
  __syncthreads();
  const int node0 = g * G8 + nl0;
  if (t < SUBN) ptr[dir * NND + node0 + t] = beg + lptr[t];
  if (sb == 2047 && t == 0) ptr[2 * NND] = 2 * NE;
  for (int i = t; i < n; i += 256) csr[beg + i] = (int)srt[i];
}

// ============ merged kernel: agg(64 rows) + dropout mask + fused GEMM ========
// Phase 1: each of 4 waves aggregates 16 rows (1 row at a time, 4x16-lane
//   row-gathers) into LDS (bf16, 16B chunks XOR-swizzled by row for
//   conflict-free GEMM reads), plus the rows' dropout keep-masks.
// Phase 2: 64x128 MFMA GEMM: A[:,0:128] from LDS, A[:,128:256] = x_dst rows
//   from global; epilogue bias + leaky-relu + mask + bf16 store.
__device__ static inline void mf_body(const u16* __restrict__ xsrc,
    const u16* __restrict__ xdst, const int* __restrict__ pd,
    const int* __restrict__ csr, const u16* __restrict__ Wsw,
    const float* __restrict__ bias, u16* __restrict__ outH,
    unsigned key0, unsigned key1, int blk)
{
  __shared__ u16 As[64 * DD];     // 16 KB
  __shared__ u64 Ms[64][2];       // 1 KB
  const int wave = threadIdx.x >> 6, lane = threadIdx.x & 63;
  const int sub = lane >> 4, l4 = lane & 15;
  const int row0 = blk * 64;

  // ---- phase 1: aggregate + mask, 16 rows per wave ----
  for (int i = 0; i < 16; ++i){
    const int lr = wave * 16 + i;
    const int row = row0 + lr;
    int beg = 0, cnt = 0;
    if (row < NN){ beg = pd[row]; cnt = pd[row + 1] - beg; }
    floatx2 p0 = (floatx2)0.f, p1 = (floatx2)0.f,
            p2 = (floatx2)0.f, p3 = (floatx2)0.f;
    int e = 0;
    for (; e + 7 < cnt; e += 8){
      int s0 = csr[beg + e + sub];
      int s1 = csr[beg + e + 4 + sub];
      uint4 v0 = *(const uint4*)(xsrc + (size_t)s0 * DD + l4 * 8);
      uint4 v1 = *(const uint4*)(xsrc + (size_t)s1 * DD + l4 * 8);
      acc4(p0, p1, p2, p3, v0);
      acc4(p0, p1, p2, p3, v1);
    }
    for (; e + 3 < cnt; e += 4){
      int s0 = csr[beg + e + sub];
      uint4 v0 = *(const uint4*)(xsrc + (size_t)s0 * DD + l4 * 8);
      acc4(p0, p1, p2, p3, v0);
    }
    if (e + sub < cnt){
      int s0 = csr[beg + e + sub];
      uint4 v0 = *(const uint4*)(xsrc + (size_t)s0 * DD + l4 * 8);
      acc4(p0, p1, p2, p3, v0);
    }
    // dropout keep-mask for this row (all 64 lanes; threefry hides under
    // the gather latency of neighboring waves)
    const int rm = (row < NN) ? row : NN - 1;
    u64 mA = __ballot(drop_keep(key0, key1, (unsigned)rm * 128u + (unsigned)lane));
    u64 mB = __ballot(drop_keep(key0, key1, (unsigned)rm * 128u + 64u + (unsigned)lane));
    if (lane == 0){ Ms[lr][0] = mA; Ms[lr][1] = mB; }
    float a[8] = { p0[0], p0[1], p1[0], p1[1], p2[0], p2[1], p3[0], p3[1] };
    #pragma unroll
    for (int j = 0; j < 8; ++j){
      a[j] += __shfl_xor(a[j], 16);
      a[j] += __shfl_xor(a[j], 32);
    }
    const float inv = (cnt > 0) ? (1.0f / (float)cnt) : 1.0f;
    if (sub == 0){
      unsigned pk[4];
      #pragma unroll
      for (int j = 0; j < 4; ++j)
        pk[j] = (unsigned)f2bf(a[2*j] * inv) | ((unsigned)f2bf(a[2*j+1] * inv) << 16);
      const int ch = l4 ^ (lr & 15);        // XOR-swizzled 16B chunk
      *(uint4*)(As + lr * DD + ch * 8) = make_uint4(pk[0], pk[1], pk[2], pk[3]);
    }
  }
  __syncthreads();

  // ---- phase 2: GEMM ----
  const int quad = lane >> 4, col0 = lane & 15;
  const int ml = wave * 16 + col0;
  int m = row0 + ml;
  if (m >= NN) m = NN - 1;

  floatx4 acc[8];
  #pragma unroll
  for (int j = 0; j < 8; ++j) acc[j] = (floatx4)0.f;

  #pragma unroll
  for (int kt = 0; kt < 8; ++kt){
    short8 a;
    if (kt < 4){
      const int k = kt * 32 + quad * 8;
      const int ch = (k >> 3) ^ (ml & 15);
      a = *(const short8*)(As + ml * DD + ch * 8);
    } else {
      const int k = (kt - 4) * 32 + quad * 8;
      a = __builtin_nontemporal_load((const short8*)(xdst + (size_t)m * 128 + k));
    }
    #pragma unroll
    for (int nt = 0; nt < 8; ++nt){
      short8 b = *(const short8*)(Wsw + (size_t)(((kt * 8 + nt) * 64 + lane) * 8));
      acc[nt] = __builtin_amdgcn_mfma_f32_16x16x32_bf16(a, b, acc[nt], 0, 0, 0);
    }
  }

  #pragma unroll
  for (int nt = 0; nt < 8; ++nt){
    const int col = nt * 16 + col0;
    const float bj = bias[col];
    const int sh = col & 63;
    #pragma unroll
    for (int rg = 0; rg < 4; ++rg){
      const int lr2 = wave * 16 + quad * 4 + rg;
      const int r = row0 + lr2;
      if (r < NN){
        float h = acc[nt][rg] + bj;
        h = (h >= 0.f) ? h : 0.01f * h;
        u64 w = Ms[lr2][nt >> 2];
        h = ((w >> sh) & 1ull) ? h * (1.0f / 0.9f) : 0.0f;
        outH[(size_t)r * 128 + col] = f2bf(h);
      }
    }
  }
}

#define GB ((NN + 63) / 64)   // 1563

// layer 0, both directions in one launch
__global__ __launch_bounds__(256) void k_mfD(
    const u16* __restrict__ Xs, const u16* __restrict__ Xt,
    const int* __restrict__ ptr, const int* __restrict__ csr,
    const u16* __restrict__ W0, const float* __restrict__ b0,
    u16* __restrict__ oB, unsigned k00, unsigned k01,
    const u16* __restrict__ W1, const float* __restrict__ b1,
    u16* __restrict__ oC, unsigned k10, unsigned k11)
{
  int b = blockIdx.x;
  if (b < GB) mf_body(Xs, Xt, ptr,       csr, W0, b0, oB, k00, k01, b);
  else        mf_body(Xt, Xs, ptr + NND, csr, W1, b1, oC, k10, k11, b - GB);
}

// layer 1, source side only
__global__ __launch_bounds__(256) void k_mf1(
    const u16* __restrict__ Bh, const u16* __restrict__ Ch,
    const int* __restrict__ ptr, const int* __restrict__ csr,
    const u16* __restrict__ W2, const float* __restrict__ b2,
    u16* __restrict__ oH, unsigned ka, unsigned kb)
{
  mf_body(Bh, Ch, ptr + NND, csr, W2, b2, oH, ka, kb, blockIdx.x);
}

// ===================== output GEMM via MFMA (fp32 out) =======================
__global__ __launch_bounds__(256) void k_out(const u16* __restrict__ H,
    const u16* __restrict__ Wsw, const float* __restrict__ bias,
    float* __restrict__ out)
{
  const int wave = threadIdx.x >> 6, lane = threadIdx.x & 63;
  const int quad = lane >> 4, col0 = lane & 15;
  const int row0 = blockIdx.x * 64 + wave * 16;
  int m = row0 + col0;
  if (m >= NN) m = NN - 1;

  floatx4 acc[4];
  #pragma unroll
  for (int i = 0; i < 4; ++i) acc[i] = (floatx4)0.f;

  #pragma unroll
  for (int kt = 0; kt < 4; ++kt){
    short8 a = __builtin_nontemporal_load(
        (const short8*)(H + (size_t)m * 128 + kt * 32 + quad * 8));
    #pragma unroll
    for (int nt = 0; nt < 4; ++nt){
      short8 b = *(const short8*)(Wsw + (size_t)(((kt * 4 + nt) * 64 + lane) * 8));
      acc[nt] = __builtin_amdgcn_mfma_f32_16x16x32_bf16(a, b, acc[nt], 0, 0, 0);
    }
  }

  #pragma unroll
  for (int nt = 0; nt < 4; ++nt){
    const int col = nt * 16 + col0;
    const float bj = bias[col];
    #pragma unroll
    for (int rg = 0; rg < 4; ++rg){
      const int r = row0 + quad * 4 + rg;
      if (r < NN)
        out[(size_t)r * 64 + col] = acc[nt][rg] + bj;
    }
  }
}

// ===================== launch =====================
extern "C" void kernel_launch(void* const* d_in, const int* in_sizes, int n_in,
                              void* d_out, int out_size, void* d_ws, size_t ws_size,
                              hipStream_t stream)
{
  const float* x_src  = (const float*)d_in[0];
  const float* x_tgt  = (const float*)d_in[1];
  const float* Wl_tgt = (const float*)d_in[2];
  const float* bl_tgt = (const float*)d_in[3];
  const float* Wr_tgt = (const float*)d_in[4];
  const float* Wl_src = (const float*)d_in[5];
  const float* bl_src = (const float*)d_in[6];
  const float* Wr_src = (const float*)d_in[7];
  const float* W_o    = (const float*)d_in[8];
  const float* b_o    = (const float*)d_in[9];
  const int*   e_src  = (const int*)d_in[10];
  const int*   e_dst  = (const int*)d_in[11];
  const int*   r_src  = (const int*)d_in[12];
  const int*   r_dst  = (const int*)d_in[13];
  float* out = (float*)d_out;
  (void)in_sizes; (void)n_in; (void)out_size; (void)ws_size;

  char* ws = (char*)d_ws;
  size_t off = 0;
  auto alloc = [&](size_t bytes) -> char* {
    char* p = ws + off; off += (bytes + 255) & ~(size_t)255; return p;
  };
  // stage1+stage2 (25.6 MB contiguous) die after k_fill4; H1 aliases them.
  unsigned* stage1 = (unsigned*)alloc((size_t)2 * NE * 4);
  unsigned* stage2 = (unsigned*)alloc((size_t)2 * NE * 4);
  u16* H1   = (u16*)stage1;                        // layer1 output (25.6 MB)
  u16* Xs   = (u16*)alloc((size_t)NN * DD * 2);
  u16* Xt   = (u16*)alloc((size_t)NN * DD * 2);
  u16* B    = (u16*)alloc((size_t)NN * DD * 2);    // h_t (layer0)
  u16* C    = (u16*)alloc((size_t)NN * DD * 2);    // h_s (layer0)
  u16* Wsw0 = (u16*)alloc(256 * 128 * 2);
  u16* Wsw1 = (u16*)alloc(256 * 128 * 2);
  u16* Wsw2 = (u16*)alloc(256 * 128 * 2);
  u16* Wswo = (u16*)alloc(128 * 64 * 2);
  int* csr  = (int*)alloc((size_t)2 * NE * 4);     // compact, node-sorted
  int* ptr  = (int*)alloc((size_t)(2 * NND + 1) * 4);
  int* hist  = (int*)alloc((size_t)(16 * HB + 1) * 4);
  int* hist2 = (int*)alloc((size_t)(16 * NSUB * K2) * 4);

  // dropout keys: fold_in(key(42), d) = threefry([0,42],[0,d]); d in {0,1,3}
  unsigned kt0a, kt0b, ks0a, ks0b, ks1a, ks1b;
  tf2x32(0u, 42u, 0u, 0u, kt0a, kt0b);   // layer0 new_t
  tf2x32(0u, 42u, 0u, 1u, ks0a, ks0b);   // layer0 new_s
  tf2x32(0u, 42u, 0u, 3u, ks1a, ks1b);   // layer1 new_s

  // fused prep: cvt + hist + weight swizzle in one launch
  k_pre<<<CVB + HB + 52, 256, 0, stream>>>(x_src, x_tgt, Xs, Xt, NN * DD / 8,
                                           e_dst, r_dst, hist,
                                           Wl_tgt, Wr_tgt, Wl_src, Wr_src, W_o,
                                           Wsw0, Wsw1, Wsw2, Wswo);
  k_scanA<<<1, 256, 0, stream>>>(hist);
  k_scatter1<<<HB, 256, 0, stream>>>(e_src, e_dst, r_src, r_dst, hist, stage1);
  k_hist2<<<16 * K2, 256, 0, stream>>>(stage1, hist, hist2);
  k_scanB<<<1, 256, 0, stream>>>(hist2);
  k_scatter2<<<16 * K2, 256, 0, stream>>>(stage1, hist, hist2, stage2);
  k_fill4<<<2048, 256, 0, stream>>>(stage2, hist2, ptr, csr);

  // layer 0: merged agg+mask+GEMM, both directions
  k_mfD<<<2 * GB, 256, 0, stream>>>(Xs, Xt, ptr, csr,
                                    Wsw0, bl_tgt, B, kt0a, kt0b,
                                    Wsw1, bl_src, C, ks0a, ks0b);
  // layer 1, source side only (layer-1 target output is dead)
  k_mf1<<<GB, 256, 0, stream>>>(B, C, ptr, csr,
                                Wsw2, bl_src + 128, H1, ks1a, ks1b);
  // out = h_s1 @ W_out + b_out
  k_out<<<GB, 256, 0, stream>>>(H1, Wswo, b_o, out);
}

// Round 8
// 550.851 us; speedup vs baseline: 1.2872x; 1.2872x over previous
//
#include <hip/hip_runtime.h>
#include <stdint.h>

#define NN 100000     // N_SRC == N_TGT
#define NE 1600000
#define DD 128
#define G8 12544      // nodes per top bucket = 128 * 98
#define SUBN 98       // nodes per sub-bucket
#define NND 100352    // padded node count = 8 * G8
#define RCAP 2304     // record cap per sub-bucket (mean 1562, sd ~40)
#define NBIN 2048     // dir(2) x range(8) x sub(128)
#define HBH 256       // hist blocks in k_pre
#define SB2 512       // scatter blocks

typedef unsigned short u16;
typedef unsigned long long u64;
typedef short short8 __attribute__((ext_vector_type(8)));
typedef float floatx4 __attribute__((ext_vector_type(4)));
typedef float floatx2 __attribute__((ext_vector_type(2)));
typedef int intx4 __attribute__((ext_vector_type(4)));

// ===================== helpers =====================
__device__ static inline u16 f2bf(float f){
  unsigned u = __float_as_uint(f);
  unsigned r = u + 0x7FFFu + ((u >> 16) & 1u);   // RNE
  return (u16)(r >> 16);
}

// ===================== threefry2x32 (JAX-compatible) =====================
__host__ __device__ static inline unsigned rotl32(unsigned x, int r){
  return (x << r) | (x >> (32 - r));
}

__host__ __device__ static inline void tf2x32(unsigned k0, unsigned k1,
                                              unsigned c0, unsigned c1,
                                              unsigned &o0, unsigned &o1)
{
  const unsigned ks2 = k0 ^ k1 ^ 0x1BD11BDAu;
  unsigned x0 = c0 + k0, x1 = c1 + k1;
#define TFR(r) { x0 += x1; x1 = rotl32(x1, (r)); x1 ^= x0; }
  TFR(13) TFR(15) TFR(26) TFR(6)   x0 += k1;  x1 += ks2 + 1u;
  TFR(17) TFR(29) TFR(16) TFR(24)  x0 += ks2; x1 += k0 + 2u;
  TFR(13) TFR(15) TFR(26) TFR(6)   x0 += k0;  x1 += k1 + 3u;
  TFR(17) TFR(29) TFR(16) TFR(24)  x0 += k1;  x1 += ks2 + 4u;
  TFR(13) TFR(15) TFR(26) TFR(6)   x0 += ks2; x1 += k0 + 5u;
#undef TFR
  o0 = x0; o1 = x1;
}

// keep-decision for one element (bit-identical to harness-verified drop_scale)
__device__ static inline int drop_keep(unsigned k0, unsigned k1, unsigned j)
{
  unsigned o0, o1;
  tf2x32(k0, k1, 0u, j, o0, o1);
  const unsigned bits = o0 ^ o1;
  const float u = __uint_as_float((bits >> 9) | 0x3F800000u) - 1.0f;
  return u < 0.9f;
}

// bf16x8 (as uint4) unpack-accumulate into packed f32x2 accumulators
__device__ static inline void acc4(floatx2 &p0, floatx2 &p1, floatx2 &p2,
                                   floatx2 &p3, uint4 v){
  floatx2 t0, t1, t2, t3;
  t0[0] = __uint_as_float(v.x << 16); t0[1] = __uint_as_float(v.x & 0xFFFF0000u);
  t1[0] = __uint_as_float(v.y << 16); t1[1] = __uint_as_float(v.y & 0xFFFF0000u);
  t2[0] = __uint_as_float(v.z << 16); t2[1] = __uint_as_float(v.z & 0xFFFF0000u);
  t3[0] = __uint_as_float(v.w << 16); t3[1] = __uint_as_float(v.w & 0xFFFF0000u);
  p0 += t0; p1 += t1; p2 += t2; p3 += t3;
}

// sub-bucket bin for a dst node: (dir<<10) | (range<<7) | sub
__device__ static inline int dbin(int dir, int d, int &nl){
  int g = d / G8;
  nl = d - g * G8;
  return (dir << 10) | (g << 7) | (nl / SUBN);
}

// ========== fused prep: cvt (12500) + 2048-bin hist (256) + weights (52) =====
#define CVB 12500
__global__ __launch_bounds__(256) void k_pre(
    const float* __restrict__ ina, const float* __restrict__ inb,
    u16* __restrict__ oa, u16* __restrict__ ob, int n8,
    const int* __restrict__ e_dst, const int* __restrict__ r_dst,
    int* __restrict__ histg,
    const float* __restrict__ Wl_tgt, const float* __restrict__ Wr_tgt,
    const float* __restrict__ Wl_src, const float* __restrict__ Wr_src,
    const float* __restrict__ Wo,
    u16* __restrict__ Wsw0, u16* __restrict__ Wsw1, u16* __restrict__ Wsw2,
    u16* __restrict__ Wswo)
{
  const int blk = blockIdx.x;
  const int t = threadIdx.x;
  if (blk < CVB){
    // -------- fp32 -> bf16 convert --------
    int i = blk * 256 + t;
    const float* in = ina; u16* out = oa;
    if (i >= n8){ i -= n8; in = inb; out = ob; }
    floatx4 a = __builtin_nontemporal_load((const floatx4*)in + (size_t)i * 2);
    floatx4 c = __builtin_nontemporal_load((const floatx4*)in + (size_t)i * 2 + 1);
    u16 v[8] = { f2bf(a[0]), f2bf(a[1]), f2bf(a[2]), f2bf(a[3]),
                 f2bf(c[0]), f2bf(c[1]), f2bf(c[2]), f2bf(c[3]) };
    *(uint4*)(out + (size_t)i * 8) = *(const uint4*)v;
  } else if (blk < CVB + HBH){
    // -------- sub-bucket histogram (2048 bins, LDS-aggregated) --------
    const int hb = blk - CVB;
    __shared__ int h2[NBIN];
    for (int i = t; i < NBIN; i += 256) h2[i] = 0;
    __syncthreads();
    const int QT = 2 * (NE / 4);
    for (int i = hb * 256 + t; i < QT; i += HBH * 256){
      int dir = (i >= NE / 4);
      int qi = dir ? i - NE / 4 : i;
      const int* dp = dir ? r_dst : e_dst;
      intx4 d = __builtin_nontemporal_load((const intx4*)dp + qi);
      int nl;
      atomicAdd(&h2[dbin(dir, d.x, nl)], 1);
      atomicAdd(&h2[dbin(dir, d.y, nl)], 1);
      atomicAdd(&h2[dbin(dir, d.z, nl)], 1);
      atomicAdd(&h2[dbin(dir, d.w, nl)], 1);
    }
    __syncthreads();
    for (int i = t; i < NBIN; i += 256){
      int c = h2[i];
      if (c) atomicAdd(&histg[i], c);
    }
  } else {
    // -------- weight pre-swizzle --------
    int b = blk - CVB - HBH;
    if (b < 48){
      const float *Wl, *Wr; u16* dst;
      if (b < 16){ Wl = Wl_tgt; Wr = Wr_tgt; dst = Wsw0; }
      else if (b < 32){ Wl = Wl_src; Wr = Wr_src; dst = Wsw1; b -= 16; }
      else { Wl = Wl_src + 16384; Wr = Wr_src + 16384; dst = Wsw2; b -= 32; }
      int idx = b * 256 + t;
      int lane = idx & 63, tile = idx >> 6;
      int kt = tile >> 3, nt = tile & 7;
      int n = nt * 16 + (lane & 15);
      int kb = kt * 32 + (lane >> 4) * 8;
      u16 v[8];
      #pragma unroll
      for (int j = 0; j < 8; ++j){
        int k = kb + j;
        float w = (k < 128) ? Wl[(size_t)k * 128 + n] : Wr[(size_t)(k - 128) * 128 + n];
        v[j] = f2bf(w);
      }
      *(uint4*)(dst + (size_t)idx * 8) = *(const uint4*)v;
    } else {
      int idx = (b - 48) * 256 + t;
      int lane = idx & 63, tile = idx >> 6;
      int kt = tile >> 2, nt = tile & 3;
      int n = nt * 16 + (lane & 15);
      int kb = kt * 32 + (lane >> 4) * 8;
      u16 v[8];
      #pragma unroll
      for (int j = 0; j < 8; ++j)
        v[j] = f2bf(Wo[(size_t)(kb + j) * 64 + n]);
      *(uint4*)(Wswo + (size_t)idx * 8) = *(const uint4*)v;
    }
  }
}

// Exclusive scan over histg[2048] -> base2 (for fill4) and gcur (working copy).
__global__ __launch_bounds__(256) void k_scan2(const int* __restrict__ histg,
                                               int* __restrict__ base2,
                                               int* __restrict__ gcur){
  __shared__ int tot[256];
  const int t = threadIdx.x;
  int v[8]; int s = 0;
  #pragma unroll
  for (int j = 0; j < 8; ++j){ v[j] = s; s += histg[t * 8 + j]; }
  tot[t] = s;
  __syncthreads();
  int mine = s;
  for (int off = 1; off < 256; off <<= 1){
    int u = (t >= off) ? tot[t - off] : 0;
    __syncthreads();
    tot[t] += u;
    __syncthreads();
  }
  int run = tot[t] - mine;
  #pragma unroll
  for (int j = 0; j < 8; ++j){
    base2[t * 8 + j] = run + v[j];
    gcur[t * 8 + j]  = run + v[j];
  }
  if (t == 0) base2[NBIN] = 2 * NE;
}

// Direct sub-bucket scatter with global-atomic reservation.
// Pass A: count my slice per bin (dst quads cached in LDS).
// Reserve: one atomicAdd per non-empty bin.
// Pass B: write records (node_local<<17)|src to reserved positions.
__global__ __launch_bounds__(256) void k_scat(const int* __restrict__ e_src,
                                              const int* __restrict__ e_dst,
                                              const int* __restrict__ r_src,
                                              const int* __restrict__ r_dst,
                                              int* __restrict__ gcur,
                                              unsigned* __restrict__ stage){
  __shared__ intx4 dq[7 * 256];           // 28 KB: cached dst quads
  __shared__ int lcnt[NBIN], lbase[NBIN], lcur[NBIN];   // 24 KB
  const int t = threadIdx.x;
  const int QT = 2 * (NE / 4);
  for (int i = t; i < NBIN; i += 256) lcnt[i] = 0;
  __syncthreads();
  {
    int j = 0;
    for (int i = blockIdx.x * 256 + t; i < QT; i += SB2 * 256, ++j){
      int dir = (i >= NE / 4);
      int qi = dir ? i - NE / 4 : i;
      const int* dp = dir ? r_dst : e_dst;
      intx4 d = __builtin_nontemporal_load((const intx4*)dp + qi);
      dq[j * 256 + t] = d;
      int nl;
      atomicAdd(&lcnt[dbin(dir, d.x, nl)], 1);
      atomicAdd(&lcnt[dbin(dir, d.y, nl)], 1);
      atomicAdd(&lcnt[dbin(dir, d.z, nl)], 1);
      atomicAdd(&lcnt[dbin(dir, d.w, nl)], 1);
    }
  }
  __syncthreads();
  for (int i = t; i < NBIN; i += 256){
    int c = lcnt[i];
    lbase[i] = c ? atomicAdd(&gcur[i], c) : 0;
    lcur[i] = 0;
  }
  __syncthreads();
  {
    int j = 0;
    for (int i = blockIdx.x * 256 + t; i < QT; i += SB2 * 256, ++j){
      int dir = (i >= NE / 4);
      int qi = dir ? i - NE / 4 : i;
      const int* sp = dir ? r_src : e_src;
      intx4 s = __builtin_nontemporal_load((const intx4*)sp + qi);
      intx4 d = dq[j * 256 + t];
      int nl, b, p;
      b = dbin(dir, d.x, nl); p = lbase[b] + atomicAdd(&lcur[b], 1);
      stage[p] = (unsigned)s.x | ((unsigned)nl << 17);
      b = dbin(dir, d.y, nl); p = lbase[b] + atomicAdd(&lcur[b], 1);
      stage[p] = (unsigned)s.y | ((unsigned)nl << 17);
      b = dbin(dir, d.z, nl); p = lbase[b] + atomicAdd(&lcur[b], 1);
      stage[p] = (unsigned)s.z | ((unsigned)nl << 17);
      b = dbin(dir, d.w, nl); p = lbase[b] + atomicAdd(&lcur[b], 1);
      stage[p] = (unsigned)s.w | ((unsigned)nl << 17);
    }
  }
}

// ===================== LDS counting-sort -> COMPACT csr + ptr ===============
__global__ __launch_bounds__(256) void k_fill4(const unsigned* __restrict__ stage,
                                               const int* __restrict__ base2,
                                               int* __restrict__ ptr,
                                               int* __restrict__ csr){
  __shared__ unsigned rec[RCAP];
  __shared__ unsigned srt[RCAP];
  __shared__ int ldeg[SUBN], lptr[SUBN], lcur[SUBN];
  const int sb = blockIdx.x;              // 0..2047
  const int b16 = sb >> 7, sub = sb & 127;
  const int dir = b16 >> 3, g = b16 & 7;
  const int t = threadIdx.x;
  const int beg = base2[sb];
  const int end = base2[sb + 1];
  int n = end - beg;
  if (n > RCAP) n = RCAP;
  for (int i = t; i < n; i += 256) rec[i] = stage[beg + i];
  if (t < SUBN) ldeg[t] = 0;
  __syncthreads();
  const int nl0 = sub * SUBN;
  for (int i = t; i < n; i += 256)
    atomicAdd(&ldeg[(int)(rec[i] >> 17) - nl0], 1);
  __syncthreads();
  if (t == 0){
    int run = 0;
    for (int s = 0; s < SUBN; ++s){ lptr[s] = run; lcur[s] = run; run += ldeg[s]; }
  }
  __syncthreads();
  for (int i = t; i < n; i += 256){
    int rl = (int)(rec[i] >> 17) - nl0;
    int pos = atomicAdd(&lcur[rl], 1);
    srt[pos] = rec[i] & 0x1FFFFu;
  }
  __syncthreads();
  const int node0 = g * G8 + nl0;
  if (t < SUBN) ptr[dir * NND + node0 + t] = beg + lptr[t];
  if (sb == 2047 && t == 0) ptr[2 * NND] = 2 * NE;
  for (int i = t; i < n; i += 256) csr[beg + i] = (int)srt[i];
}

// ===================== mean aggregation body =================================
// 1 wave/row; 4 lane-groups of 16; 16-deep edge unroll = 4 outstanding
// row-gathers per lane. Packed floatx2 accumulators. Optional keep-mask.
template<bool WM>
__device__ static inline void agg_body(const u16* __restrict__ x,
                                       const int* __restrict__ pd,
                                       const int* __restrict__ csr,
                                       u16* __restrict__ out,
                                       u64* __restrict__ msk,
                                       unsigned key0, unsigned key1, int blk){
  const int row = blk * 4 + (threadIdx.x >> 6);
  const int lane = threadIdx.x & 63;
  const int sub = lane >> 4, l4 = lane & 15;
  const int beg = pd[row], end = pd[row + 1];
  const int cnt = end - beg;
  floatx2 p0 = (floatx2)0.f, p1 = (floatx2)0.f, p2 = (floatx2)0.f, p3 = (floatx2)0.f;
  int e = 0;
  for (; e + 15 < cnt; e += 16){
    int s0 = csr[beg + e + sub];
    int s1 = csr[beg + e + 4 + sub];
    int s2 = csr[beg + e + 8 + sub];
    int s3 = csr[beg + e + 12 + sub];
    uint4 v0 = *(const uint4*)(x + (size_t)s0 * DD + l4 * 8);
    uint4 v1 = *(const uint4*)(x + (size_t)s1 * DD + l4 * 8);
    uint4 v2 = *(const uint4*)(x + (size_t)s2 * DD + l4 * 8);
    uint4 v3 = *(const uint4*)(x + (size_t)s3 * DD + l4 * 8);
    acc4(p0, p1, p2, p3, v0);
    acc4(p0, p1, p2, p3, v1);
    acc4(p0, p1, p2, p3, v2);
    acc4(p0, p1, p2, p3, v3);
  }
  for (; e + 7 < cnt; e += 8){
    int s0 = csr[beg + e + sub];
    int s1 = csr[beg + e + 4 + sub];
    uint4 v0 = *(const uint4*)(x + (size_t)s0 * DD + l4 * 8);
    uint4 v1 = *(const uint4*)(x + (size_t)s1 * DD + l4 * 8);
    acc4(p0, p1, p2, p3, v0);
    acc4(p0, p1, p2, p3, v1);
  }
  for (; e + 3 < cnt; e += 4){
    int s0 = csr[beg + e + sub];
    uint4 v0 = *(const uint4*)(x + (size_t)s0 * DD + l4 * 8);
    acc4(p0, p1, p2, p3, v0);
  }
  if (e + sub < cnt){
    int s0 = csr[beg + e + sub];
    uint4 v0 = *(const uint4*)(x + (size_t)s0 * DD + l4 * 8);
    acc4(p0, p1, p2, p3, v0);
  }
  if (WM){
    // dropout keep-mask for this row: 2 threefry/lane + 2 ballots
    u64 mA = __ballot(drop_keep(key0, key1, (unsigned)row * 128u + (unsigned)lane));
    u64 mB = __ballot(drop_keep(key0, key1, (unsigned)row * 128u + 64u + (unsigned)lane));
    if (lane < 2) msk[(size_t)row * 2 + lane] = lane ? mB : mA;
  }
  float a[8] = { p0[0], p0[1], p1[0], p1[1], p2[0], p2[1], p3[0], p3[1] };
  #pragma unroll
  for (int i = 0; i < 8; ++i){
    a[i] += __shfl_xor(a[i], 16);
    a[i] += __shfl_xor(a[i], 32);
  }
  const float inv = (cnt > 0) ? (1.0f / (float)cnt) : 1.0f;
  if (sub == 0){
    unsigned pk[4];
    #pragma unroll
    for (int i = 0; i < 4; ++i)
      pk[i] = (unsigned)f2bf(a[2*i] * inv) | ((unsigned)f2bf(a[2*i+1] * inv) << 16);
    *(uint4*)(out + (size_t)row * DD + l4 * 8) = make_uint4(pk[0], pk[1], pk[2], pk[3]);
  }
}

// dual-direction agg (layer 0): both dirs emit keep-masks (R2 placement)
__global__ __launch_bounds__(256) void k_aggD(const u16* __restrict__ x0,
    const u16* __restrict__ x1, const int* __restrict__ ptr,
    const int* __restrict__ csr, u16* __restrict__ o0, u16* __restrict__ o1,
    u64* __restrict__ m0, u64* __restrict__ m1,
    unsigned k00, unsigned k01, unsigned k10, unsigned k11){
  int b = blockIdx.x;
  if (b < NN / 4) agg_body<true>(x0, ptr, csr, o0, m0, k00, k01, b);
  else            agg_body<true>(x1, ptr + NND, csr, o1, m1, k10, k11, b - NN / 4);
}

// single-direction agg (layer 1, dir1) + M1s mask
__global__ __launch_bounds__(256) void k_agg1(const u16* __restrict__ x,
    const int* __restrict__ ptr, const int* __restrict__ csr,
    u16* __restrict__ out, u64* __restrict__ msk,
    unsigned key0, unsigned key1){
  agg_body<true>(x, ptr + NND, csr, out, msk, key0, key1, blockIdx.x);
}

// ===================== fused layer GEMM body =================================
// Dropout masks are precomputed (2 u64 per row) — epilogue is bit-test+select.
__device__ static inline void fused_body(const u16* __restrict__ Am,
    const u16* __restrict__ X, const u16* __restrict__ Wsw,
    const float* __restrict__ bias, u16* __restrict__ outH,
    const u64* __restrict__ msk, int blk)
{
  const int wave = threadIdx.x >> 6, lane = threadIdx.x & 63;
  const int quad = lane >> 4, col0 = lane & 15;
  const int row0 = blk * 64 + wave * 16;
  int m = row0 + col0;
  if (m >= NN) m = NN - 1;

  floatx4 acc[8];
  #pragma unroll
  for (int i = 0; i < 8; ++i) acc[i] = (floatx4)0.f;

  #pragma unroll
  for (int kt = 0; kt < 8; ++kt){
    const int k = kt * 32 + quad * 8;
    const u16* ap = (k < 128) ? (Am + (size_t)m * 128 + k)
                              : (X  + (size_t)m * 128 + (k - 128));
    short8 a = __builtin_nontemporal_load((const short8*)ap);
    #pragma unroll
    for (int nt = 0; nt < 8; ++nt){
      short8 b = *(const short8*)(Wsw + (size_t)(((kt * 8 + nt) * 64 + lane) * 8));
      acc[nt] = __builtin_amdgcn_mfma_f32_16x16x32_bf16(a, b, acc[nt], 0, 0, 0);
    }
  }

  // per-row keep masks for my 4 rows (L2-resident, broadcast within quad)
  u64 w0[4], w1[4];
  #pragma unroll
  for (int rg = 0; rg < 4; ++rg){
    int r = row0 + quad * 4 + rg;
    size_t rr = (size_t)((r < NN) ? r : (NN - 1)) * 2;
    w0[rg] = msk[rr];
    w1[rg] = msk[rr + 1];
  }

  #pragma unroll
  for (int nt = 0; nt < 8; ++nt){
    const int col = nt * 16 + col0;
    const float bj = bias[col];
    const int sh = col & 63;
    #pragma unroll
    for (int rg = 0; rg < 4; ++rg){
      const int r = row0 + quad * 4 + rg;
      if (r < NN){
        float h = acc[nt][rg] + bj;
        h = (h >= 0.f) ? h : 0.01f * h;
        u64 w = (nt < 4) ? w0[rg] : w1[rg];
        h = ((w >> sh) & 1ull) ? h * (1.0f / 0.9f) : 0.0f;
        outH[(size_t)r * 128 + col] = f2bf(h);
      }
    }
  }
}

#define GB ((NN + 63) / 64)   // 1563

// dual fused GEMM (layer 0, both sides in one launch)
__global__ __launch_bounds__(256) void k_fusedD(
    const u16* __restrict__ A0, const u16* __restrict__ X0,
    const u16* __restrict__ W0, const float* __restrict__ b0,
    u16* __restrict__ o0, const u64* __restrict__ m0,
    const u16* __restrict__ A1, const u16* __restrict__ X1,
    const u16* __restrict__ W1, const float* __restrict__ b1,
    u16* __restrict__ o1, const u64* __restrict__ m1)
{
  int b = blockIdx.x;
  if (b < GB) fused_body(A0, X0, W0, b0, o0, m0, b);
  else        fused_body(A1, X1, W1, b1, o1, m1, b - GB);
}

__global__ __launch_bounds__(256) void k_fused(const u16* __restrict__ Am,
    const u16* __restrict__ X, const u16* __restrict__ Wsw,
    const float* __restrict__ bias, u16* __restrict__ outH,
    const u64* __restrict__ msk)
{
  fused_body(Am, X, Wsw, bias, outH, msk, blockIdx.x);
}

// ===================== output GEMM via MFMA (fp32 out) =======================
__global__ __launch_bounds__(256) void k_out(const u16* __restrict__ H,
    const u16* __restrict__ Wsw, const float* __restrict__ bias,
    float* __restrict__ out)
{
  const int wave = threadIdx.x >> 6, lane = threadIdx.x & 63;
  const int quad = lane >> 4, col0 = lane & 15;
  const int row0 = blockIdx.x * 64 + wave * 16;
  int m = row0 + col0;
  if (m >= NN) m = NN - 1;

  floatx4 acc[4];
  #pragma unroll
  for (int i = 0; i < 4; ++i) acc[i] = (floatx4)0.f;

  #pragma unroll
  for (int kt = 0; kt < 4; ++kt){
    short8 a = __builtin_nontemporal_load(
        (const short8*)(H + (size_t)m * 128 + kt * 32 + quad * 8));
    #pragma unroll
    for (int nt = 0; nt < 4; ++nt){
      short8 b = *(const short8*)(Wsw + (size_t)(((kt * 4 + nt) * 64 + lane) * 8));
      acc[nt] = __builtin_amdgcn_mfma_f32_16x16x32_bf16(a, b, acc[nt], 0, 0, 0);
    }
  }

  #pragma unroll
  for (int nt = 0; nt < 4; ++nt){
    const int col = nt * 16 + col0;
    const float bj = bias[col];
    #pragma unroll
    for (int rg = 0; rg < 4; ++rg){
      const int r = row0 + quad * 4 + rg;
      if (r < NN)
        out[(size_t)r * 64 + col] = acc[nt][rg] + bj;
    }
  }
}

// ===================== launch =====================
extern "C" void kernel_launch(void* const* d_in, const int* in_sizes, int n_in,
                              void* d_out, int out_size, void* d_ws, size_t ws_size,
                              hipStream_t stream)
{
  const float* x_src  = (const float*)d_in[0];
  const float* x_tgt  = (const float*)d_in[1];
  const float* Wl_tgt = (const float*)d_in[2];
  const float* bl_tgt = (const float*)d_in[3];
  const float* Wr_tgt = (const float*)d_in[4];
  const float* Wl_src = (const float*)d_in[5];
  const float* bl_src = (const float*)d_in[6];
  const float* Wr_src = (const float*)d_in[7];
  const float* W_o    = (const float*)d_in[8];
  const float* b_o    = (const float*)d_in[9];
  const int*   e_src  = (const int*)d_in[10];
  const int*   e_dst  = (const int*)d_in[11];
  const int*   r_src  = (const int*)d_in[12];
  const int*   r_dst  = (const int*)d_in[13];
  float* out = (float*)d_out;
  (void)in_sizes; (void)n_in; (void)out_size; (void)ws_size;

  char* ws = (char*)d_ws;
  size_t off = 0;
  auto alloc = [&](size_t bytes) -> char* {
    char* p = ws + off; off += (bytes + 255) & ~(size_t)255; return p;
  };
  // stage (12.8 MB used; 25.6 reserved) dies after k_fill4; A_t aliases it.
  unsigned* stage = (unsigned*)alloc((size_t)2 * NE * 8);
  u16* A_t  = (u16*)stage;                         // 25.6 MB alias
  u16* A_s  = (u16*)alloc((size_t)NN * DD * 2);
  u16* Xs   = (u16*)alloc((size_t)NN * DD * 2);
  u16* Xt   = (u16*)alloc((size_t)NN * DD * 2);
  u16* B    = (u16*)alloc((size_t)NN * DD * 2);    // h_t(l0), then h_s(l1)
  u16* C    = (u16*)alloc((size_t)NN * DD * 2);    // h_s(l0)
  u16* Wsw0 = (u16*)alloc(256 * 128 * 2);
  u16* Wsw1 = (u16*)alloc(256 * 128 * 2);
  u16* Wsw2 = (u16*)alloc(256 * 128 * 2);
  u16* Wswo = (u16*)alloc(128 * 64 * 2);
  int* csr  = (int*)alloc((size_t)2 * NE * 4);     // compact, node-sorted
  int* ptr  = (int*)alloc((size_t)(2 * NND + 1) * 4);
  int* histg = (int*)alloc((size_t)NBIN * 4);
  int* base2 = (int*)alloc((size_t)(NBIN + 1) * 4);
  int* gcur  = (int*)alloc((size_t)NBIN * 4);
  u64* M0t  = (u64*)alloc((size_t)NN * 2 * 8);     // layer0 target keep-mask
  u64* M0s  = (u64*)alloc((size_t)NN * 2 * 8);     // layer0 source keep-mask
  u64* M1s  = (u64*)alloc((size_t)NN * 2 * 8);     // layer1 source keep-mask

  // dropout keys: fold_in(key(42), d) = threefry([0,42],[0,d]); d in {0,1,3}
  unsigned kt0a, kt0b, ks0a, ks0b, ks1a, ks1b;
  tf2x32(0u, 42u, 0u, 0u, kt0a, kt0b);   // layer0 new_t
  tf2x32(0u, 42u, 0u, 1u, ks0a, ks0b);   // layer0 new_s
  tf2x32(0u, 42u, 0u, 3u, ks1a, ks1b);   // layer1 new_s

  hipMemsetAsync(histg, 0, (size_t)NBIN * 4, stream);
  // fused prep: cvt + 2048-bin hist + weight swizzle in one launch
  k_pre<<<CVB + HBH + 52, 256, 0, stream>>>(x_src, x_tgt, Xs, Xt, NN * DD / 8,
                                            e_dst, r_dst, histg,
                                            Wl_tgt, Wr_tgt, Wl_src, Wr_src, W_o,
                                            Wsw0, Wsw1, Wsw2, Wswo);
  k_scan2<<<1, 256, 0, stream>>>(histg, base2, gcur);
  k_scat<<<SB2, 256, 0, stream>>>(e_src, e_dst, r_src, r_dst, gcur, stage);
  k_fill4<<<2048, 256, 0, stream>>>(stage, base2, ptr, csr);

  const int AB = NN / 4;            // 25000
  // layer 0: both directions; masks computed in-agg (R2 placement)
  k_aggD<<<2 * AB, 256, 0, stream>>>(Xs, Xt, ptr, csr, A_t, A_s,
                                     M0t, M0s, kt0a, kt0b, ks0a, ks0b);
  k_fusedD<<<2 * GB, 256, 0, stream>>>(A_t, Xt, Wsw0, bl_tgt, B, M0t,
                                       A_s, Xs, Wsw1, bl_src, C, M0s);
  // layer 1, source side only (layer-1 target output is dead); emits M1s
  k_agg1<<<AB, 256, 0, stream>>>(B, ptr, csr, A_t, M1s, ks1a, ks1b);
  k_fused<<<GB, 256, 0, stream>>>(A_t, C, Wsw2, bl_src + 128, B, M1s);
  // out = h_s1 @ W_out + b_out
  k_out<<<GB, 256, 0, stream>>>(B, Wswo, b_o, out);
}